// Round 5
// baseline (325.384 us; speedup 1.0000x reference)
//
#include <hip/hip_runtime.h>

#define NN 50000
#define EE 300000
#define ET (EE + NN)   // edges + self loops = 350000
#define CD 256
#define PAD_M 50176    // 196 * 256, covers gemm tile over-read
#define NB 196         // scan blocks: 196*256 = 50176 >= NN

typedef unsigned short ushortT;
typedef short bf16x8 __attribute__((ext_vector_type(8)));
typedef float f32x4 __attribute__((ext_vector_type(4)));

__device__ __forceinline__ ushortT f2b(float f) {
    unsigned u = __builtin_bit_cast(unsigned, f);
    unsigned r = (u + 0x7FFFu + ((u >> 16) & 1u)) >> 16;
    return (ushortT)r;
}
__device__ __forceinline__ float b2f(ushortT b) {
    return __builtin_bit_cast(float, ((unsigned)b) << 16);
}

// ---------------- fused preprocessing ----------------
// flat grid of block roles:
//   [0,12500)        cast x -> B0 (bf16)
//   [12500,12564)    transpose-cast W1 -> W1t
//   [12564,12628)    transpose-cast W2 -> W2t
//   [12628,12692)    straight-cast Wl -> Wlt
//   [12692,12888)    init deg=1, zero alpha buffers (A and B sets)
#define PREP_X 12500
#define PREP_W1 12564
#define PREP_W2 12628
#define PREP_WL 12692
#define PREP_END 12888

__global__ __launch_bounds__(256) void prep_kernel(
    const float* __restrict__ x, const float* __restrict__ W1,
    const float* __restrict__ W2, const float* __restrict__ Wl,
    ushortT* __restrict__ B0, ushortT* __restrict__ W1t,
    ushortT* __restrict__ W2t, ushortT* __restrict__ Wlt,
    int* __restrict__ deg, float* __restrict__ asA, float* __restrict__ adA,
    float* __restrict__ asB, float* __restrict__ adB) {
    __shared__ float t[32][33];
    int b = blockIdx.x, tidx = threadIdx.x;
    if (b < PREP_X) {
        int id = b * 256 + tidx;
        float4 v = *(const float4*)(x + (size_t)id * 4);
        ushort4 o;
        o.x = f2b(v.x); o.y = f2b(v.y); o.z = f2b(v.z); o.w = f2b(v.w);
        *(ushort4*)(B0 + (size_t)id * 4) = o;
    } else if (b < PREP_W2) {
        const float* W = (b < PREP_W1) ? W1 : W2;
        ushortT* Bt = (b < PREP_W1) ? W1t : W2t;
        int rel = b - ((b < PREP_W1) ? PREP_X : PREP_W1);
        int bx = (rel & 7) * 32;   // k base
        int by = (rel >> 3) * 32;  // n base
        int xx = tidx & 31, yy = tidx >> 5;
        for (int y = yy; y < 32; y += 8) t[y][xx] = W[(size_t)(bx + y) * CD + by + xx];
        __syncthreads();
        for (int y = yy; y < 32; y += 8)
            Bt[(size_t)(by + y) * CD + bx + xx] = f2b(t[xx][y]);
    } else if (b < PREP_WL) {
        int id = (b - PREP_W2) * 256 + tidx;
        float4 v = *(const float4*)(Wl + (size_t)id * 4);
        ushort4 o;
        o.x = f2b(v.x); o.y = f2b(v.y); o.z = f2b(v.z); o.w = f2b(v.w);
        *(ushort4*)(Wlt + (size_t)id * 4) = o;
    } else {
        int i = (b - PREP_WL) * 256 + tidx;
        if (i < NN) {
            deg[i] = 1;  // self loop
            asA[i] = 0.f; adA[i] = 0.f;
            asB[i] = 0.f; adB[i] = 0.f;
        }
    }
}

// ---------------- CSR build ----------------

__global__ void count_deg_kernel(const int* __restrict__ ei, int* __restrict__ deg) {
    int i = blockIdx.x * blockDim.x + threadIdx.x;
    if (i < EE) atomicAdd(&deg[ei[EE + i]], 1);  // dst row of edge_index
}

__global__ __launch_bounds__(256) void scan_part(const int* __restrict__ deg,
                                                 int* __restrict__ bsum) {
    int i = blockIdx.x * 256 + threadIdx.x;
    int v = (i < NN) ? deg[i] : 0;
#pragma unroll
    for (int off = 32; off > 0; off >>= 1) v += __shfl_down(v, off);
    __shared__ int w[4];
    if ((threadIdx.x & 63) == 0) w[threadIdx.x >> 6] = v;
    __syncthreads();
    if (threadIdx.x == 0) bsum[blockIdx.x] = w[0] + w[1] + w[2] + w[3];
}

__global__ __launch_bounds__(256) void scan_top(const int* __restrict__ bsum,
                                                int* __restrict__ boffs,
                                                int* __restrict__ row_start) {
    __shared__ int s[256];
    int t = threadIdx.x;
    int v = (t < NB) ? bsum[t] : 0;
    s[t] = v;
    __syncthreads();
    for (int off = 1; off < 256; off <<= 1) {
        int x = s[t];
        int y = (t >= off) ? s[t - off] : 0;
        __syncthreads();
        s[t] = x + y;
        __syncthreads();
    }
    if (t < NB) boffs[t] = s[t] - v;  // exclusive
    if (t == 0) row_start[NN] = ET;
}

__global__ __launch_bounds__(256) void scan_fill(const int* __restrict__ deg,
                                                 const int* __restrict__ boffs,
                                                 int* __restrict__ row_start,
                                                 int* __restrict__ fill_pos) {
    __shared__ int s[256];
    int t = threadIdx.x;
    int i = blockIdx.x * 256 + t;
    int v = (i < NN) ? deg[i] : 0;
    s[t] = v;
    __syncthreads();
    for (int off = 1; off < 256; off <<= 1) {
        int x = s[t];
        int y = (t >= off) ? s[t - off] : 0;
        __syncthreads();
        s[t] = x + y;
        __syncthreads();
    }
    int excl = s[t] - v + boffs[blockIdx.x];
    if (i < NN) {
        row_start[i] = excl;
        fill_pos[i] = excl;
    }
}

__global__ void fill_csr_kernel(const int* __restrict__ ei, int* __restrict__ fill_pos,
                                int* __restrict__ srcs) {
    int i = blockIdx.x * blockDim.x + threadIdx.x;
    if (i < EE) {
        int s = ei[i];
        int d = ei[EE + i];
        int p = atomicAdd(&fill_pos[d], 1);
        srcs[p] = s;
    } else if (i < ET) {
        int n = i - EE;
        int p = atomicAdd(&fill_pos[n], 1);
        srcs[p] = n;  // self loop
    }
}

// ---------------- bf16 MFMA GEMM: C[M,256] = A[M,256] @ Bt^T ----------------
// Block = 256 rows x 64 cols. This block's 64-col B slice (32 KB) staged ONCE
// into LDS (16B-chunk xor-swizzle), then barrier-free K-loop, A fragments
// loaded global->register (A re-reads across the 4 col-blocks are L3-hits).
// 32 KB LDS + <=128 VGPR -> 4-5 resident blocks/CU (vs 2 at 64 KB), which is
// the latency-hiding the R4 version lacked.
// OUTF32=1: fp32 out + bias. OUTF32=0: bf16 out (padded ws, unconditional).
// ALPHA=1: as_[row] += C[row,:]@a_src etc. from the fp32 accumulator.

template <int OUTF32, int ALPHA>
__global__ __launch_bounds__(256, 4) void gemm_mfma(const ushortT* __restrict__ A,
                                                    const ushortT* __restrict__ Bt,
                                                    const float* __restrict__ bias,
                                                    float* __restrict__ outF,
                                                    ushortT* __restrict__ outB,
                                                    const float* __restrict__ a_src,
                                                    const float* __restrict__ a_dst,
                                                    float* __restrict__ as_g,
                                                    float* __restrict__ ad_g,
                                                    int M) {
    __shared__ ushortT Bs[64 * 256];  // 32 KB, n-major, 16B-chunk xor-swizzle
    int tid = threadIdx.x;
    int wave = tid >> 6, lane = tid & 63;
    int wm = wave * 64;                    // wave's 64-row slice of the 256-row block
    int bm = blockIdx.x * 256, bn = blockIdx.y * 64;
    int l15 = lane & 15, quad = lane >> 4;

    // ---- stage B slice: 64 rows x 32 chunks = 2048 16B chunks, 8 rounds ----
#pragma unroll
    for (int p = 0; p < 8; ++p) {
        int c = p * 256 + tid;             // lane-linear flat chunk id
        int row = c >> 5;                  // 32 chunks per 256-elem row
        int piece = c & 31;
        int spiece = piece ^ (row & 31);   // physical chunk p holds data chunk p^row
        const ushortT* gb = Bt + (size_t)(bn + row) * CD + spiece * 8;
        __builtin_amdgcn_global_load_lds(
            (const __attribute__((address_space(1))) void*)gb,
            (__attribute__((address_space(3))) void*)(Bs + (size_t)(p * 256 + wave * 64) * 8),
            16, 0, 0);
    }
    __syncthreads();

    f32x4 acc[4][4] = {};

    // ---- barrier-free K loop: 8 x K32 steps ----
#pragma unroll
    for (int kk = 0; kk < 8; ++kk) {
        bf16x8 a[4], b[4];
#pragma unroll
        for (int i = 0; i < 4; ++i)
            a[i] = *(const bf16x8*)(A + (size_t)(bm + wm + i * 16 + l15) * CD + kk * 32 + quad * 8);
        int kc = kk * 4 + quad;  // data chunk index within row
#pragma unroll
        for (int j = 0; j < 4; ++j) {
            int n_local = j * 16 + l15;
            b[j] = *(const bf16x8*)(Bs + (size_t)n_local * 256 + (size_t)(kc ^ (n_local & 31)) * 8);
        }
#pragma unroll
        for (int i = 0; i < 4; ++i)
#pragma unroll
            for (int j = 0; j < 4; ++j)
                acc[i][j] = __builtin_amdgcn_mfma_f32_16x16x32_bf16(a[i], b[j], acc[i][j], 0, 0, 0);
    }

    // ---- epilogue ----
#pragma unroll
    for (int i = 0; i < 4; ++i) {
#pragma unroll
        for (int j = 0; j < 4; ++j) {
            int col = bn + j * 16 + l15;
            int row0 = bm + wm + i * 16 + quad * 4;
#pragma unroll
            for (int r = 0; r < 4; ++r) {
                int row = row0 + r;
                float v = acc[i][j][r];
                if (OUTF32) {
                    if (row < M) outF[(size_t)row * CD + col] = v + bias[col];
                } else {
                    outB[(size_t)row * CD + col] = f2b(v);  // ws padded, no check
                }
            }
        }
    }

    if (ALPHA) {
        float avs[4], avd[4];
#pragma unroll
        for (int j = 0; j < 4; ++j) {
            int col = bn + j * 16 + l15;
            avs[j] = a_src[col];
            avd[j] = a_dst[col];
        }
#pragma unroll
        for (int i = 0; i < 4; ++i) {
#pragma unroll
            for (int r = 0; r < 4; ++r) {
                int row = bm + wm + i * 16 + quad * 4 + r;
                float ps = 0.f, pd = 0.f;
#pragma unroll
                for (int j = 0; j < 4; ++j) {
                    float v = acc[i][j][r];
                    ps += v * avs[j];
                    pd += v * avd[j];
                }
#pragma unroll
                for (int off = 1; off < 16; off <<= 1) {  // xor stays in-quad
                    ps += __shfl_xor(ps, off);
                    pd += __shfl_xor(pd, off);
                }
                if (l15 == 0 && row < M) {
                    atomicAdd(&as_g[row], ps);
                    atomicAdd(&ad_g[row], pd);
                }
            }
        }
    }
}

// ---------------- GAT aggregation: one wave per dst node (bf16 h, bf16 out) ----------------

__device__ __forceinline__ float lrelu02(float x) { return x > 0.f ? x : 0.2f * x; }

__global__ __launch_bounds__(256) void gat_agg(const ushortT* __restrict__ h,
                                               const float* __restrict__ as_,
                                               const float* __restrict__ ad_,
                                               const int* __restrict__ row_start,
                                               const int* __restrict__ srcs,
                                               const float* __restrict__ bias,
                                               ushortT* __restrict__ out) {
    int node = blockIdx.x * 4 + (threadIdx.x >> 6);
    int lane = threadIdx.x & 63;
    if (node >= NN) return;
    int rs = row_start[node];
    int re = row_start[node + 1];
    int deg = re - rs;
    float adst = ad_[node];

    float a0 = 0.f, a1 = 0.f, a2 = 0.f, a3 = 0.f;

    if (deg <= 64) {
        // ---- fast path: softmax entirely in-register, ILP-8 gather ----
        int s_lane = srcs[rs + ((lane < deg) ? lane : 0)];
        float e = (lane < deg) ? lrelu02(as_[s_lane] + adst) : -1e30f;
        float m = e;
#pragma unroll
        for (int off = 1; off < 64; off <<= 1) m = fmaxf(m, __shfl_xor(m, off));
        float ex = (lane < deg) ? __expf(e - m) : 0.f;
        float den = ex;
#pragma unroll
        for (int off = 1; off < 64; off <<= 1) den += __shfl_xor(den, off);
        float wl = ex / den;  // per-lane edge weight (0 for invalid lanes)

        for (int kk = 0; kk < deg; kk += 8) {
            int s[8];
            float w[8];
#pragma unroll
            for (int t = 0; t < 8; ++t) {
                int idx = kk + t;                 // wave-uniform
                int ii = (idx < deg) ? idx : kk;  // clamp to a valid lane
                int sv = __shfl(s_lane, ii);
                float wv = __shfl(wl, ii);
                s[t] = sv;
                w[t] = (idx < deg) ? wv : 0.f;
            }
            ushort4 hv[8];
#pragma unroll
            for (int t = 0; t < 8; ++t)
                hv[t] = *(const ushort4*)(h + (size_t)s[t] * CD + lane * 4);
#pragma unroll
            for (int t = 0; t < 8; ++t) {
                a0 += w[t] * b2f(hv[t].x);
                a1 += w[t] * b2f(hv[t].y);
                a2 += w[t] * b2f(hv[t].z);
                a3 += w[t] * b2f(hv[t].w);
            }
        }
    } else {
        // ---- generic path (deg > 64): strided loops ----
        float m = -1e30f;
        for (int k = rs + lane; k < re; k += 64) {
            float e = lrelu02(as_[srcs[k]] + adst);
            m = fmaxf(m, e);
        }
#pragma unroll
        for (int off = 1; off < 64; off <<= 1) m = fmaxf(m, __shfl_xor(m, off));
        float den = 0.f;
        for (int k = rs + lane; k < re; k += 64) {
            float e = lrelu02(as_[srcs[k]] + adst);
            den += __expf(e - m);
        }
#pragma unroll
        for (int off = 1; off < 64; off <<= 1) den += __shfl_xor(den, off);
        float inv_den = 1.f / den;
        for (int k = rs; k < re; ++k) {
            int s = srcs[k];
            float e = lrelu02(as_[s] + adst);
            float w = __expf(e - m) * inv_den;
            ushort4 hv = *(const ushort4*)(h + (size_t)s * CD + lane * 4);
            a0 += w * b2f(hv.x);
            a1 += w * b2f(hv.y);
            a2 += w * b2f(hv.z);
            a3 += w * b2f(hv.w);
        }
    }

    float4 b4 = *(const float4*)(bias + lane * 4);
    a0 = fmaxf(a0 + b4.x, 0.f);  // bias + relu (both convs feed relu)
    a1 = fmaxf(a1 + b4.y, 0.f);
    a2 = fmaxf(a2 + b4.z, 0.f);
    a3 = fmaxf(a3 + b4.w, 0.f);
    ushort4 o;
    o.x = f2b(a0);
    o.y = f2b(a1);
    o.z = f2b(a2);
    o.w = f2b(a3);
    *(ushort4*)(out + (size_t)node * CD + lane * 4) = o;
}

// ---------------- launch ----------------

extern "C" void kernel_launch(void* const* d_in, const int* in_sizes, int n_in,
                              void* d_out, int out_size, void* d_ws, size_t ws_size,
                              hipStream_t stream) {
    const float* x = (const float*)d_in[0];
    const int* ei = (const int*)d_in[1];
    const float* W1 = (const float*)d_in[2];
    const float* a1s = (const float*)d_in[3];
    const float* a1d = (const float*)d_in[4];
    const float* b1 = (const float*)d_in[5];
    const float* W2 = (const float*)d_in[6];
    const float* a2s = (const float*)d_in[7];
    const float* a2d = (const float*)d_in[8];
    const float* b2 = (const float*)d_in[9];
    const float* Wl = (const float*)d_in[10];
    const float* bl = (const float*)d_in[11];
    float* out = (float*)d_out;

    char* w = (char*)d_ws;
    ushortT* B0 = (ushortT*)w; w += (size_t)PAD_M * CD * 2;
    ushortT* B1 = (ushortT*)w; w += (size_t)PAD_M * CD * 2;
    ushortT* B2 = (ushortT*)w; w += (size_t)PAD_M * CD * 2;
    ushortT* W1t = (ushortT*)w; w += (size_t)CD * CD * 2;
    ushortT* W2t = (ushortT*)w; w += (size_t)CD * CD * 2;
    ushortT* Wlt = (ushortT*)w; w += (size_t)CD * CD * 2;
    float* asA = (float*)w; w += (size_t)NN * 4;
    float* adA = (float*)w; w += (size_t)NN * 4;
    float* asB = (float*)w; w += (size_t)NN * 4;
    float* adB = (float*)w; w += (size_t)NN * 4;
    int* deg = (int*)w; w += (size_t)NN * 4;
    int* fill_pos = (int*)w; w += (size_t)NN * 4;
    int* srcs = (int*)w; w += (size_t)ET * 4;
    int* bsum = (int*)w; w += 1024;
    int* boffs = (int*)w; w += 1024;
    int* row_start = (int*)w; w += (size_t)(NN + 1) * 4;

    // fused preprocessing: casts + deg/alpha init
    prep_kernel<<<PREP_END, 256, 0, stream>>>(x, W1, W2, Wl, B0, W1t, W2t, Wlt,
                                              deg, asA, adA, asB, adB);

    // CSR build
    count_deg_kernel<<<(EE + 255) / 256, 256, 0, stream>>>(ei, deg);
    scan_part<<<NB, 256, 0, stream>>>(deg, bsum);
    scan_top<<<1, 256, 0, stream>>>(bsum, boffs, row_start);
    scan_fill<<<NB, 256, 0, stream>>>(deg, boffs, row_start, fill_pos);
    fill_csr_kernel<<<(ET + 255) / 256, 256, 0, stream>>>(ei, fill_pos, srcs);

    dim3 ggrid(PAD_M / 256, 4);   // 196 x 4 = 784 blocks of 256 rows x 64 cols
    int nwave_blocks = (NN + 3) / 4;

    // Layer 1 (alpha fused into GEMM epilogue, A buffers)
    gemm_mfma<0, 1><<<ggrid, 256, 0, stream>>>(B0, W1t, nullptr, nullptr, B1,
                                               a1s, a1d, asA, adA, NN);
    gat_agg<<<nwave_blocks, 256, 0, stream>>>(B1, asA, adA, row_start, srcs, b1, B2);

    // Layer 2 (B buffers — pre-zeroed in prep, no zero dispatch needed)
    gemm_mfma<0, 1><<<ggrid, 256, 0, stream>>>(B2, W2t, nullptr, nullptr, B1,
                                               a2s, a2d, asB, adB, NN);
    gat_agg<<<nwave_blocks, 256, 0, stream>>>(B1, asB, adB, row_start, srcs, b2, B0);

    // Final linear: out = B0 @ Wlt^T + bl (fp32 out)
    gemm_mfma<1, 0><<<ggrid, 256, 0, stream>>>(B0, Wlt, bl, out, nullptr,
                                               nullptr, nullptr, nullptr, nullptr, NN);
}

// Round 6
// 295.528 us; speedup vs baseline: 1.1010x; 1.1010x over previous
//
#include <hip/hip_runtime.h>

#define NN 50000
#define EE 300000
#define ET (EE + NN)   // edges + self loops = 350000
#define CD 256
#define PAD_M 50176    // 392 * 128, covers gemm tile over-read
#define NB 196         // scan blocks: 196*256 = 50176 >= NN

typedef unsigned short ushortT;
typedef short bf16x8 __attribute__((ext_vector_type(8)));
typedef float f32x4 __attribute__((ext_vector_type(4)));

__device__ __forceinline__ ushortT f2b(float f) {
    unsigned u = __builtin_bit_cast(unsigned, f);
    unsigned r = (u + 0x7FFFu + ((u >> 16) & 1u)) >> 16;
    return (ushortT)r;
}
__device__ __forceinline__ float b2f(ushortT b) {
    return __builtin_bit_cast(float, ((unsigned)b) << 16);
}

// ---------------- fused preprocessing ----------------
#define PREP_X 12500
#define PREP_W1 12564
#define PREP_W2 12628
#define PREP_WL 12692
#define PREP_END 12888

__global__ __launch_bounds__(256) void prep_kernel(
    const float* __restrict__ x, const float* __restrict__ W1,
    const float* __restrict__ W2, const float* __restrict__ Wl,
    ushortT* __restrict__ B0, ushortT* __restrict__ W1t,
    ushortT* __restrict__ W2t, ushortT* __restrict__ Wlt,
    int* __restrict__ deg, float* __restrict__ asA, float* __restrict__ adA,
    float* __restrict__ asB, float* __restrict__ adB) {
    __shared__ float t[32][33];
    int b = blockIdx.x, tidx = threadIdx.x;
    if (b < PREP_X) {
        int id = b * 256 + tidx;
        float4 v = *(const float4*)(x + (size_t)id * 4);
        ushort4 o;
        o.x = f2b(v.x); o.y = f2b(v.y); o.z = f2b(v.z); o.w = f2b(v.w);
        *(ushort4*)(B0 + (size_t)id * 4) = o;
    } else if (b < PREP_W2) {
        const float* W = (b < PREP_W1) ? W1 : W2;
        ushortT* Bt = (b < PREP_W1) ? W1t : W2t;
        int rel = b - ((b < PREP_W1) ? PREP_X : PREP_W1);
        int bx = (rel & 7) * 32;   // k base
        int by = (rel >> 3) * 32;  // n base
        int xx = tidx & 31, yy = tidx >> 5;
        for (int y = yy; y < 32; y += 8) t[y][xx] = W[(size_t)(bx + y) * CD + by + xx];
        __syncthreads();
        for (int y = yy; y < 32; y += 8)
            Bt[(size_t)(by + y) * CD + bx + xx] = f2b(t[xx][y]);
    } else if (b < PREP_WL) {
        int id = (b - PREP_W2) * 256 + tidx;
        float4 v = *(const float4*)(Wl + (size_t)id * 4);
        ushort4 o;
        o.x = f2b(v.x); o.y = f2b(v.y); o.z = f2b(v.z); o.w = f2b(v.w);
        *(ushort4*)(Wlt + (size_t)id * 4) = o;
    } else {
        int i = (b - PREP_WL) * 256 + tidx;
        if (i < NN) {
            deg[i] = 1;  // self loop
            asA[i] = 0.f; adA[i] = 0.f;
            asB[i] = 0.f; adB[i] = 0.f;
        }
    }
}

// ---------------- CSR build ----------------

__global__ void count_deg_kernel(const int* __restrict__ ei, int* __restrict__ deg) {
    int i = blockIdx.x * blockDim.x + threadIdx.x;
    if (i < EE) atomicAdd(&deg[ei[EE + i]], 1);  // dst row of edge_index
}

__global__ __launch_bounds__(256) void scan_part(const int* __restrict__ deg,
                                                 int* __restrict__ bsum) {
    int i = blockIdx.x * 256 + threadIdx.x;
    int v = (i < NN) ? deg[i] : 0;
#pragma unroll
    for (int off = 32; off > 0; off >>= 1) v += __shfl_down(v, off);
    __shared__ int w[4];
    if ((threadIdx.x & 63) == 0) w[threadIdx.x >> 6] = v;
    __syncthreads();
    if (threadIdx.x == 0) bsum[blockIdx.x] = w[0] + w[1] + w[2] + w[3];
}

__global__ __launch_bounds__(256) void scan_top(const int* __restrict__ bsum,
                                                int* __restrict__ boffs,
                                                int* __restrict__ row_start) {
    __shared__ int s[256];
    int t = threadIdx.x;
    int v = (t < NB) ? bsum[t] : 0;
    s[t] = v;
    __syncthreads();
    for (int off = 1; off < 256; off <<= 1) {
        int x = s[t];
        int y = (t >= off) ? s[t - off] : 0;
        __syncthreads();
        s[t] = x + y;
        __syncthreads();
    }
    if (t < NB) boffs[t] = s[t] - v;  // exclusive
    if (t == 0) row_start[NN] = ET;
}

__global__ __launch_bounds__(256) void scan_fill(const int* __restrict__ deg,
                                                 const int* __restrict__ boffs,
                                                 int* __restrict__ row_start,
                                                 int* __restrict__ fill_pos) {
    __shared__ int s[256];
    int t = threadIdx.x;
    int i = blockIdx.x * 256 + t;
    int v = (i < NN) ? deg[i] : 0;
    s[t] = v;
    __syncthreads();
    for (int off = 1; off < 256; off <<= 1) {
        int x = s[t];
        int y = (t >= off) ? s[t - off] : 0;
        __syncthreads();
        s[t] = x + y;
        __syncthreads();
    }
    int excl = s[t] - v + boffs[blockIdx.x];
    if (i < NN) {
        row_start[i] = excl;
        fill_pos[i] = excl;
    }
}

__global__ void fill_csr_kernel(const int* __restrict__ ei, int* __restrict__ fill_pos,
                                int* __restrict__ srcs) {
    int i = blockIdx.x * blockDim.x + threadIdx.x;
    if (i < EE) {
        int s = ei[i];
        int d = ei[EE + i];
        int p = atomicAdd(&fill_pos[d], 1);
        srcs[p] = s;
    } else if (i < ET) {
        int n = i - EE;
        int p = atomicAdd(&fill_pos[n], 1);
        srcs[p] = n;  // self loop
    }
}

// ---------------- bf16 MFMA GEMM: C[M,256] = A[M,256] @ Bt^T ----------------
// Block = 128 rows x 64 cols; grid 392 x 4 = 1568 blocks (~6/CU queued,
// LDS 32 KB -> exactly 5 resident blocks/CU = 20 waves/CU).
// B slice staged ONCE into LDS with TWO transforms:
//   - column permutation: LDS slot n holds actual col (n&15)*4 + (n>>4), so
//     the MFMA C/D lane l15 ends up owning 4 CONTIGUOUS output cols across
//     its j registers -> packed 8B/16B epilogue stores (kills the 2x HBM
//     write amplification measured in R5: WRITE 53MB for 25.6MB of data).
//   - 16B-chunk xor swizzle by row: kills LDS bank conflicts (verified 0).
// Barrier-free K-loop; A fragments global->register (L2/L3-resident re-reads).

template <int OUTF32, int ALPHA>
__global__ __launch_bounds__(256, 4) void gemm_mfma(const ushortT* __restrict__ A,
                                                    const ushortT* __restrict__ Bt,
                                                    const float* __restrict__ bias,
                                                    float* __restrict__ outF,
                                                    ushortT* __restrict__ outB,
                                                    const float* __restrict__ a_src,
                                                    const float* __restrict__ a_dst,
                                                    float* __restrict__ as_g,
                                                    float* __restrict__ ad_g,
                                                    int M) {
    __shared__ ushortT Bs[64 * 256];  // 32 KB
    int tid = threadIdx.x;
    int wave = tid >> 6, lane = tid & 63;
    int wm = wave * 32;                    // wave's 32-row slice of 128-row block
    int bm = blockIdx.x * 128, bn = blockIdx.y * 64;
    int l15 = lane & 15, quad = lane >> 4;

    // ---- stage B slice: 64 slots x 32 chunks = 2048 16B chunks, 8 rounds ----
#pragma unroll
    for (int p = 0; p < 8; ++p) {
        int c = p * 256 + tid;             // lane-linear flat chunk id
        int slot = c >> 5;                 // LDS slot (permuted col)
        int piece = c & 31;
        int col = (slot & 15) * 4 + (slot >> 4);   // actual col for this slot
        int spiece = piece ^ (slot & 31);  // physical chunk p holds data chunk p^slot
        const ushortT* gb = Bt + (size_t)(bn + col) * CD + spiece * 8;
        __builtin_amdgcn_global_load_lds(
            (const __attribute__((address_space(1))) void*)gb,
            (__attribute__((address_space(3))) void*)(Bs + (size_t)(p * 256 + wave * 64) * 8),
            16, 0, 0);
    }
    __syncthreads();

    f32x4 acc[2][4] = {};

    // ---- barrier-free K loop: 8 x K32 steps ----
#pragma unroll
    for (int kk = 0; kk < 8; ++kk) {
        bf16x8 a[2], b[4];
#pragma unroll
        for (int i = 0; i < 2; ++i)
            a[i] = *(const bf16x8*)(A + (size_t)(bm + wm + i * 16 + l15) * CD + kk * 32 + quad * 8);
        int kc = kk * 4 + quad;  // data chunk index within slot
#pragma unroll
        for (int j = 0; j < 4; ++j) {
            int slot = j * 16 + l15;
            b[j] = *(const bf16x8*)(Bs + (size_t)slot * 256 + (size_t)(kc ^ (slot & 31)) * 8);
        }
#pragma unroll
        for (int i = 0; i < 2; ++i)
#pragma unroll
            for (int j = 0; j < 4; ++j)
                acc[i][j] = __builtin_amdgcn_mfma_f32_16x16x32_bf16(a[i], b[j], acc[i][j], 0, 0, 0);
    }

    // ---- epilogue: lane l15 owns 4 contiguous cols bn+4*l15.. across j ----
    int colb = bn + l15 * 4;
#pragma unroll
    for (int i = 0; i < 2; ++i) {
#pragma unroll
        for (int r = 0; r < 4; ++r) {
            int row = bm + wm + i * 16 + quad * 4 + r;
            if (OUTF32) {
                if (row < M) {
                    float4 bv = *(const float4*)(bias + colb);
                    float4 v;
                    v.x = acc[i][0][r] + bv.x;
                    v.y = acc[i][1][r] + bv.y;
                    v.z = acc[i][2][r] + bv.z;
                    v.w = acc[i][3][r] + bv.w;
                    *(float4*)(outF + (size_t)row * CD + colb) = v;
                }
            } else {
                ushort4 o;
                o.x = f2b(acc[i][0][r]);
                o.y = f2b(acc[i][1][r]);
                o.z = f2b(acc[i][2][r]);
                o.w = f2b(acc[i][3][r]);
                *(ushort4*)(outB + (size_t)row * CD + colb) = o;  // ws padded
            }
        }
    }

    if (ALPHA) {
        float4 avs = *(const float4*)(a_src + colb);
        float4 avd = *(const float4*)(a_dst + colb);
#pragma unroll
        for (int i = 0; i < 2; ++i) {
#pragma unroll
            for (int r = 0; r < 4; ++r) {
                int row = bm + wm + i * 16 + quad * 4 + r;
                float ps = acc[i][0][r] * avs.x + acc[i][1][r] * avs.y +
                           acc[i][2][r] * avs.z + acc[i][3][r] * avs.w;
                float pd = acc[i][0][r] * avd.x + acc[i][1][r] * avd.y +
                           acc[i][2][r] * avd.z + acc[i][3][r] * avd.w;
#pragma unroll
                for (int off = 1; off < 16; off <<= 1) {  // xor stays in-quad
                    ps += __shfl_xor(ps, off);
                    pd += __shfl_xor(pd, off);
                }
                if (l15 == 0 && row < M) {
                    atomicAdd(&as_g[row], ps);
                    atomicAdd(&ad_g[row], pd);
                }
            }
        }
    }
}

// ---------------- GAT aggregation: one wave per dst node (bf16 h, bf16 out) ----------------

__device__ __forceinline__ float lrelu02(float x) { return x > 0.f ? x : 0.2f * x; }

__global__ __launch_bounds__(256) void gat_agg(const ushortT* __restrict__ h,
                                               const float* __restrict__ as_,
                                               const float* __restrict__ ad_,
                                               const int* __restrict__ row_start,
                                               const int* __restrict__ srcs,
                                               const float* __restrict__ bias,
                                               ushortT* __restrict__ out) {
    int node = blockIdx.x * 4 + (threadIdx.x >> 6);
    int lane = threadIdx.x & 63;
    if (node >= NN) return;
    int rs = row_start[node];
    int re = row_start[node + 1];
    int deg = re - rs;
    float adst = ad_[node];

    float a0 = 0.f, a1 = 0.f, a2 = 0.f, a3 = 0.f;

    if (deg <= 64) {
        // ---- fast path: softmax entirely in-register, ILP-8 gather ----
        int s_lane = srcs[rs + ((lane < deg) ? lane : 0)];
        float e = (lane < deg) ? lrelu02(as_[s_lane] + adst) : -1e30f;
        float m = e;
#pragma unroll
        for (int off = 1; off < 64; off <<= 1) m = fmaxf(m, __shfl_xor(m, off));
        float ex = (lane < deg) ? __expf(e - m) : 0.f;
        float den = ex;
#pragma unroll
        for (int off = 1; off < 64; off <<= 1) den += __shfl_xor(den, off);
        float wl = ex / den;  // per-lane edge weight (0 for invalid lanes)

        for (int kk = 0; kk < deg; kk += 8) {
            int s[8];
            float w[8];
#pragma unroll
            for (int t = 0; t < 8; ++t) {
                int idx = kk + t;                 // wave-uniform
                int ii = (idx < deg) ? idx : kk;  // clamp to a valid lane
                int sv = __shfl(s_lane, ii);
                float wv = __shfl(wl, ii);
                s[t] = sv;
                w[t] = (idx < deg) ? wv : 0.f;
            }
            ushort4 hv[8];
#pragma unroll
            for (int t = 0; t < 8; ++t)
                hv[t] = *(const ushort4*)(h + (size_t)s[t] * CD + lane * 4);
#pragma unroll
            for (int t = 0; t < 8; ++t) {
                a0 += w[t] * b2f(hv[t].x);
                a1 += w[t] * b2f(hv[t].y);
                a2 += w[t] * b2f(hv[t].z);
                a3 += w[t] * b2f(hv[t].w);
            }
        }
    } else {
        // ---- generic path (deg > 64): strided loops ----
        float m = -1e30f;
        for (int k = rs + lane; k < re; k += 64) {
            float e = lrelu02(as_[srcs[k]] + adst);
            m = fmaxf(m, e);
        }
#pragma unroll
        for (int off = 1; off < 64; off <<= 1) m = fmaxf(m, __shfl_xor(m, off));
        float den = 0.f;
        for (int k = rs + lane; k < re; k += 64) {
            float e = lrelu02(as_[srcs[k]] + adst);
            den += __expf(e - m);
        }
#pragma unroll
        for (int off = 1; off < 64; off <<= 1) den += __shfl_xor(den, off);
        float inv_den = 1.f / den;
        for (int k = rs; k < re; ++k) {
            int s = srcs[k];
            float e = lrelu02(as_[s] + adst);
            float w = __expf(e - m) * inv_den;
            ushort4 hv = *(const ushort4*)(h + (size_t)s * CD + lane * 4);
            a0 += w * b2f(hv.x);
            a1 += w * b2f(hv.y);
            a2 += w * b2f(hv.z);
            a3 += w * b2f(hv.w);
        }
    }

    float4 b4 = *(const float4*)(bias + lane * 4);
    a0 = fmaxf(a0 + b4.x, 0.f);  // bias + relu (both convs feed relu)
    a1 = fmaxf(a1 + b4.y, 0.f);
    a2 = fmaxf(a2 + b4.z, 0.f);
    a3 = fmaxf(a3 + b4.w, 0.f);
    ushort4 o;
    o.x = f2b(a0);
    o.y = f2b(a1);
    o.z = f2b(a2);
    o.w = f2b(a3);
    *(ushort4*)(out + (size_t)node * CD + lane * 4) = o;
}

// ---------------- launch ----------------

extern "C" void kernel_launch(void* const* d_in, const int* in_sizes, int n_in,
                              void* d_out, int out_size, void* d_ws, size_t ws_size,
                              hipStream_t stream) {
    const float* x = (const float*)d_in[0];
    const int* ei = (const int*)d_in[1];
    const float* W1 = (const float*)d_in[2];
    const float* a1s = (const float*)d_in[3];
    const float* a1d = (const float*)d_in[4];
    const float* b1 = (const float*)d_in[5];
    const float* W2 = (const float*)d_in[6];
    const float* a2s = (const float*)d_in[7];
    const float* a2d = (const float*)d_in[8];
    const float* b2 = (const float*)d_in[9];
    const float* Wl = (const float*)d_in[10];
    const float* bl = (const float*)d_in[11];
    float* out = (float*)d_out;

    char* w = (char*)d_ws;
    ushortT* B0 = (ushortT*)w; w += (size_t)PAD_M * CD * 2;
    ushortT* B1 = (ushortT*)w; w += (size_t)PAD_M * CD * 2;
    ushortT* B2 = (ushortT*)w; w += (size_t)PAD_M * CD * 2;
    ushortT* W1t = (ushortT*)w; w += (size_t)CD * CD * 2;
    ushortT* W2t = (ushortT*)w; w += (size_t)CD * CD * 2;
    ushortT* Wlt = (ushortT*)w; w += (size_t)CD * CD * 2;
    float* asA = (float*)w; w += (size_t)NN * 4;
    float* adA = (float*)w; w += (size_t)NN * 4;
    float* asB = (float*)w; w += (size_t)NN * 4;
    float* adB = (float*)w; w += (size_t)NN * 4;
    int* deg = (int*)w; w += (size_t)NN * 4;
    int* fill_pos = (int*)w; w += (size_t)NN * 4;
    int* srcs = (int*)w; w += (size_t)ET * 4;
    int* bsum = (int*)w; w += 1024;
    int* boffs = (int*)w; w += 1024;
    int* row_start = (int*)w; w += (size_t)(NN + 1) * 4;

    // fused preprocessing: casts + deg/alpha init
    prep_kernel<<<PREP_END, 256, 0, stream>>>(x, W1, W2, Wl, B0, W1t, W2t, Wlt,
                                              deg, asA, adA, asB, adB);

    // CSR build
    count_deg_kernel<<<(EE + 255) / 256, 256, 0, stream>>>(ei, deg);
    scan_part<<<NB, 256, 0, stream>>>(deg, bsum);
    scan_top<<<1, 256, 0, stream>>>(bsum, boffs, row_start);
    scan_fill<<<NB, 256, 0, stream>>>(deg, boffs, row_start, fill_pos);
    fill_csr_kernel<<<(ET + 255) / 256, 256, 0, stream>>>(ei, fill_pos, srcs);

    dim3 ggrid(PAD_M / 128, 4);   // 392 x 4 = 1568 blocks of 128 rows x 64 cols
    int nwave_blocks = (NN + 3) / 4;

    // Layer 1 (alpha fused into GEMM epilogue, A buffers)
    gemm_mfma<0, 1><<<ggrid, 256, 0, stream>>>(B0, W1t, nullptr, nullptr, B1,
                                               a1s, a1d, asA, adA, NN);
    gat_agg<<<nwave_blocks, 256, 0, stream>>>(B1, asA, adA, row_start, srcs, b1, B2);

    // Layer 2 (B buffers — pre-zeroed in prep, no zero dispatch needed)
    gemm_mfma<0, 1><<<ggrid, 256, 0, stream>>>(B2, W2t, nullptr, nullptr, B1,
                                               a2s, a2d, asB, adB, NN);
    gat_agg<<<nwave_blocks, 256, 0, stream>>>(B1, asB, adB, row_start, srcs, b2, B0);

    // Final linear: out = B0 @ Wlt^T + bl (fp32 out)
    gemm_mfma<1, 0><<<ggrid, 256, 0, stream>>>(B0, Wlt, bl, out, nullptr,
                                               nullptr, nullptr, nullptr, nullptr, NN);
}

// Round 7
// 295.142 us; speedup vs baseline: 1.1025x; 1.0013x over previous
//
#include <hip/hip_runtime.h>

#define NN 50000
#define EE 300000
#define ET (EE + NN)   // edges + self loops = 350000
#define CD 256
#define PAD_M 50176    // 392 * 128, covers gemm tile over-read
#define NB 196         // scan blocks: 196*256 = 50176 >= NN

typedef unsigned short ushortT;
typedef short bf16x8 __attribute__((ext_vector_type(8)));
typedef float f32x4 __attribute__((ext_vector_type(4)));

__device__ __forceinline__ ushortT f2b(float f) {
    unsigned u = __builtin_bit_cast(unsigned, f);
    unsigned r = (u + 0x7FFFu + ((u >> 16) & 1u)) >> 16;
    return (ushortT)r;
}
__device__ __forceinline__ float b2f(ushortT b) {
    return __builtin_bit_cast(float, ((unsigned)b) << 16);
}

// ---------------- fused preprocessing ----------------
#define PREP_X 12500
#define PREP_W1 12564
#define PREP_W2 12628
#define PREP_WL 12692
#define PREP_END 12888

__global__ __launch_bounds__(256) void prep_kernel(
    const float* __restrict__ x, const float* __restrict__ W1,
    const float* __restrict__ W2, const float* __restrict__ Wl,
    ushortT* __restrict__ B0, ushortT* __restrict__ W1t,
    ushortT* __restrict__ W2t, ushortT* __restrict__ Wlt,
    int* __restrict__ deg, float* __restrict__ asA, float* __restrict__ adA,
    float* __restrict__ asB, float* __restrict__ adB) {
    __shared__ float t[32][33];
    int b = blockIdx.x, tidx = threadIdx.x;
    if (b < PREP_X) {
        int id = b * 256 + tidx;
        float4 v = *(const float4*)(x + (size_t)id * 4);
        ushort4 o;
        o.x = f2b(v.x); o.y = f2b(v.y); o.z = f2b(v.z); o.w = f2b(v.w);
        *(ushort4*)(B0 + (size_t)id * 4) = o;
    } else if (b < PREP_W2) {
        const float* W = (b < PREP_W1) ? W1 : W2;
        ushortT* Bt = (b < PREP_W1) ? W1t : W2t;
        int rel = b - ((b < PREP_W1) ? PREP_X : PREP_W1);
        int bx = (rel & 7) * 32;   // k base
        int by = (rel >> 3) * 32;  // n base
        int xx = tidx & 31, yy = tidx >> 5;
        for (int y = yy; y < 32; y += 8) t[y][xx] = W[(size_t)(bx + y) * CD + by + xx];
        __syncthreads();
        for (int y = yy; y < 32; y += 8)
            Bt[(size_t)(by + y) * CD + bx + xx] = f2b(t[xx][y]);
    } else if (b < PREP_WL) {
        int id = (b - PREP_W2) * 256 + tidx;
        float4 v = *(const float4*)(Wl + (size_t)id * 4);
        ushort4 o;
        o.x = f2b(v.x); o.y = f2b(v.y); o.z = f2b(v.z); o.w = f2b(v.w);
        *(ushort4*)(Wlt + (size_t)id * 4) = o;
    } else {
        int i = (b - PREP_WL) * 256 + tidx;
        if (i < NN) {
            deg[i] = 1;  // self loop
            asA[i] = 0.f; adA[i] = 0.f;
            asB[i] = 0.f; adB[i] = 0.f;
        }
    }
}

// ---------------- CSR build ----------------

__global__ void count_deg_kernel(const int* __restrict__ ei, int* __restrict__ deg) {
    int i = blockIdx.x * blockDim.x + threadIdx.x;
    if (i < EE) atomicAdd(&deg[ei[EE + i]], 1);  // dst row of edge_index
}

__global__ __launch_bounds__(256) void scan_part(const int* __restrict__ deg,
                                                 int* __restrict__ bsum) {
    int i = blockIdx.x * 256 + threadIdx.x;
    int v = (i < NN) ? deg[i] : 0;
#pragma unroll
    for (int off = 32; off > 0; off >>= 1) v += __shfl_down(v, off);
    __shared__ int w[4];
    if ((threadIdx.x & 63) == 0) w[threadIdx.x >> 6] = v;
    __syncthreads();
    if (threadIdx.x == 0) bsum[blockIdx.x] = w[0] + w[1] + w[2] + w[3];
}

// scan_fill with the top-level 196-partial scan folded in (each block
// redundantly scans bsum — 196 ints, trivial — saving one dispatch).
__global__ __launch_bounds__(256) void scan_fill(const int* __restrict__ deg,
                                                 const int* __restrict__ bsum,
                                                 int* __restrict__ row_start,
                                                 int* __restrict__ fill_pos) {
    __shared__ int s[256];
    int t = threadIdx.x;
    // top scan of block partials
    int bv = (t < NB) ? bsum[t] : 0;
    s[t] = bv;
    __syncthreads();
    for (int off = 1; off < 256; off <<= 1) {
        int x = s[t];
        int y = (t >= off) ? s[t - off] : 0;
        __syncthreads();
        s[t] = x + y;
        __syncthreads();
    }
    int boff = s[blockIdx.x] - bsum[blockIdx.x];  // exclusive prefix for this block
    __syncthreads();
    // per-element scan within this block
    int i = blockIdx.x * 256 + t;
    int v = (i < NN) ? deg[i] : 0;
    s[t] = v;
    __syncthreads();
    for (int off = 1; off < 256; off <<= 1) {
        int x = s[t];
        int y = (t >= off) ? s[t - off] : 0;
        __syncthreads();
        s[t] = x + y;
        __syncthreads();
    }
    int excl = s[t] - v + boff;
    if (i < NN) {
        row_start[i] = excl;
        fill_pos[i] = excl;
    }
    if (blockIdx.x == 0 && t == 0) row_start[NN] = ET;
}

__global__ void fill_csr_kernel(const int* __restrict__ ei, int* __restrict__ fill_pos,
                                int* __restrict__ srcs) {
    int i = blockIdx.x * blockDim.x + threadIdx.x;
    if (i < EE) {
        int s = ei[i];
        int d = ei[EE + i];
        int p = atomicAdd(&fill_pos[d], 1);
        srcs[p] = s;
    } else if (i < ET) {
        int n = i - EE;
        int p = atomicAdd(&fill_pos[n], 1);
        srcs[p] = n;  // self loop
    }
}

// ---------------- bf16 MFMA GEMM: C[M,256] = A[M,256] @ Bt^T ----------------
// Block = 128 rows x 64 cols, 1-D grid 1568, swizzled so the 4 col-blocks
// sharing the same A rows are temporally adjacent (L2/L3 A-reuse).
// ALL A fragments (a[2][8], full K) hoisted into registers before the
// barrier, issued concurrently with the B global_load_lds staging — the
// K-loop then has ZERO global-latency exposure (R5/R6's VGPR=64 showed the
// compiler was NOT hoisting; 8 serialized ~500cyc stalls was the 5% MfmaUtil).
// B LDS layout: column-permuted (slot n -> col (n&15)*4+(n>>4)) so lane l15
// owns 4 contiguous output cols -> packed stores; 16B-chunk xor swizzle for
// bank conflicts (measured 0).

template <int OUTF32, int ALPHA>
__global__ __launch_bounds__(256, 4) void gemm_mfma(const ushortT* __restrict__ A,
                                                    const ushortT* __restrict__ Bt,
                                                    const float* __restrict__ bias,
                                                    float* __restrict__ outF,
                                                    ushortT* __restrict__ outB,
                                                    const float* __restrict__ a_src,
                                                    const float* __restrict__ a_dst,
                                                    float* __restrict__ as_g,
                                                    float* __restrict__ ad_g,
                                                    int M) {
    __shared__ ushortT Bs[64 * 256];  // 32 KB
    int tid = threadIdx.x;
    int wave = tid >> 6, lane = tid & 63;
    int wm = wave * 32;                    // wave's 32-row slice of 128-row block
    int id = blockIdx.x;
    int bm = (id >> 2) * 128, bn = (id & 3) * 64;
    int l15 = lane & 15, quad = lane >> 4;

    // ---- B staging: 64 slots x 32 chunks = 2048 16B chunks, 8 rounds ----
#pragma unroll
    for (int p = 0; p < 8; ++p) {
        int c = p * 256 + tid;             // lane-linear flat chunk id
        int slot = c >> 5;                 // LDS slot (permuted col)
        int piece = c & 31;
        int col = (slot & 15) * 4 + (slot >> 4);   // actual col for this slot
        int spiece = piece ^ (slot & 31);  // physical chunk p holds data chunk p^slot
        const ushortT* gb = Bt + (size_t)(bn + col) * CD + spiece * 8;
        __builtin_amdgcn_global_load_lds(
            (const __attribute__((address_space(1))) void*)gb,
            (__attribute__((address_space(3))) void*)(Bs + (size_t)(p * 256 + wave * 64) * 8),
            16, 0, 0);
    }

    // ---- hoist ALL A fragments (16 independent 16B loads, in flight
    //      concurrently with the B staging above) ----
    bf16x8 a[2][8];
#pragma unroll
    for (int kk = 0; kk < 8; ++kk)
#pragma unroll
        for (int i = 0; i < 2; ++i)
            a[i][kk] = *(const bf16x8*)(A + (size_t)(bm + wm + i * 16 + l15) * CD + kk * 32 + quad * 8);

    __syncthreads();

    f32x4 acc[2][4] = {};

    // ---- K loop: pure LDS + MFMA ----
#pragma unroll
    for (int kk = 0; kk < 8; ++kk) {
        bf16x8 b[4];
        int kc = kk * 4 + quad;  // data chunk index within slot
#pragma unroll
        for (int j = 0; j < 4; ++j) {
            int slot = j * 16 + l15;
            b[j] = *(const bf16x8*)(Bs + (size_t)slot * 256 + (size_t)(kc ^ (slot & 31)) * 8);
        }
#pragma unroll
        for (int i = 0; i < 2; ++i)
#pragma unroll
            for (int j = 0; j < 4; ++j)
                acc[i][j] = __builtin_amdgcn_mfma_f32_16x16x32_bf16(a[i][kk], b[j], acc[i][j], 0, 0, 0);
    }

    // ---- epilogue: lane l15 owns 4 contiguous cols bn+4*l15.. across j ----
    int colb = bn + l15 * 4;
#pragma unroll
    for (int i = 0; i < 2; ++i) {
#pragma unroll
        for (int r = 0; r < 4; ++r) {
            int row = bm + wm + i * 16 + quad * 4 + r;
            if (OUTF32) {
                if (row < M) {
                    float4 bv = *(const float4*)(bias + colb);
                    float4 v;
                    v.x = acc[i][0][r] + bv.x;
                    v.y = acc[i][1][r] + bv.y;
                    v.z = acc[i][2][r] + bv.z;
                    v.w = acc[i][3][r] + bv.w;
                    *(float4*)(outF + (size_t)row * CD + colb) = v;
                }
            } else {
                ushort4 o;
                o.x = f2b(acc[i][0][r]);
                o.y = f2b(acc[i][1][r]);
                o.z = f2b(acc[i][2][r]);
                o.w = f2b(acc[i][3][r]);
                *(ushort4*)(outB + (size_t)row * CD + colb) = o;  // ws padded
            }
        }
    }

    if (ALPHA) {
        float4 avs = *(const float4*)(a_src + colb);
        float4 avd = *(const float4*)(a_dst + colb);
#pragma unroll
        for (int i = 0; i < 2; ++i) {
#pragma unroll
            for (int r = 0; r < 4; ++r) {
                int row = bm + wm + i * 16 + quad * 4 + r;
                float ps = acc[i][0][r] * avs.x + acc[i][1][r] * avs.y +
                           acc[i][2][r] * avs.z + acc[i][3][r] * avs.w;
                float pd = acc[i][0][r] * avd.x + acc[i][1][r] * avd.y +
                           acc[i][2][r] * avd.z + acc[i][3][r] * avd.w;
#pragma unroll
                for (int off = 1; off < 16; off <<= 1) {  // xor stays in-quad
                    ps += __shfl_xor(ps, off);
                    pd += __shfl_xor(pd, off);
                }
                if (l15 == 0 && row < M) {
                    atomicAdd(&as_g[row], ps);
                    atomicAdd(&ad_g[row], pd);
                }
            }
        }
    }
}

// ---------------- GAT aggregation: one wave per dst node (bf16 h, bf16 out) ----------------

__device__ __forceinline__ float lrelu02(float x) { return x > 0.f ? x : 0.2f * x; }

__global__ __launch_bounds__(256) void gat_agg(const ushortT* __restrict__ h,
                                               const float* __restrict__ as_,
                                               const float* __restrict__ ad_,
                                               const int* __restrict__ row_start,
                                               const int* __restrict__ srcs,
                                               const float* __restrict__ bias,
                                               ushortT* __restrict__ out) {
    int node = blockIdx.x * 4 + (threadIdx.x >> 6);
    int lane = threadIdx.x & 63;
    if (node >= NN) return;
    int rs = row_start[node];
    int re = row_start[node + 1];
    int deg = re - rs;
    float adst = ad_[node];

    float a0 = 0.f, a1 = 0.f, a2 = 0.f, a3 = 0.f;

    if (deg <= 64) {
        // ---- fast path: softmax entirely in-register, ILP-8 gather ----
        int s_lane = srcs[rs + ((lane < deg) ? lane : 0)];
        float e = (lane < deg) ? lrelu02(as_[s_lane] + adst) : -1e30f;
        float m = e;
#pragma unroll
        for (int off = 1; off < 64; off <<= 1) m = fmaxf(m, __shfl_xor(m, off));
        float ex = (lane < deg) ? __expf(e - m) : 0.f;
        float den = ex;
#pragma unroll
        for (int off = 1; off < 64; off <<= 1) den += __shfl_xor(den, off);
        float wl = ex / den;  // per-lane edge weight (0 for invalid lanes)

        for (int kk = 0; kk < deg; kk += 8) {
            int s[8];
            float w[8];
#pragma unroll
            for (int t = 0; t < 8; ++t) {
                int idx = kk + t;                 // wave-uniform
                int ii = (idx < deg) ? idx : kk;  // clamp to a valid lane
                int sv = __shfl(s_lane, ii);
                float wv = __shfl(wl, ii);
                s[t] = sv;
                w[t] = (idx < deg) ? wv : 0.f;
            }
            ushort4 hv[8];
#pragma unroll
            for (int t = 0; t < 8; ++t)
                hv[t] = *(const ushort4*)(h + (size_t)s[t] * CD + lane * 4);
#pragma unroll
            for (int t = 0; t < 8; ++t) {
                a0 += w[t] * b2f(hv[t].x);
                a1 += w[t] * b2f(hv[t].y);
                a2 += w[t] * b2f(hv[t].z);
                a3 += w[t] * b2f(hv[t].w);
            }
        }
    } else {
        // ---- generic path (deg > 64): strided loops ----
        float m = -1e30f;
        for (int k = rs + lane; k < re; k += 64) {
            float e = lrelu02(as_[srcs[k]] + adst);
            m = fmaxf(m, e);
        }
#pragma unroll
        for (int off = 1; off < 64; off <<= 1) m = fmaxf(m, __shfl_xor(m, off));
        float den = 0.f;
        for (int k = rs + lane; k < re; k += 64) {
            float e = lrelu02(as_[srcs[k]] + adst);
            den += __expf(e - m);
        }
#pragma unroll
        for (int off = 1; off < 64; off <<= 1) den += __shfl_xor(den, off);
        float inv_den = 1.f / den;
        for (int k = rs; k < re; ++k) {
            int s = srcs[k];
            float e = lrelu02(as_[s] + adst);
            float w = __expf(e - m) * inv_den;
            ushort4 hv = *(const ushort4*)(h + (size_t)s * CD + lane * 4);
            a0 += w * b2f(hv.x);
            a1 += w * b2f(hv.y);
            a2 += w * b2f(hv.z);
            a3 += w * b2f(hv.w);
        }
    }

    float4 b4 = *(const float4*)(bias + lane * 4);
    a0 = fmaxf(a0 + b4.x, 0.f);  // bias + relu (both convs feed relu)
    a1 = fmaxf(a1 + b4.y, 0.f);
    a2 = fmaxf(a2 + b4.z, 0.f);
    a3 = fmaxf(a3 + b4.w, 0.f);
    ushort4 o;
    o.x = f2b(a0);
    o.y = f2b(a1);
    o.z = f2b(a2);
    o.w = f2b(a3);
    *(ushort4*)(out + (size_t)node * CD + lane * 4) = o;
}

// ---------------- launch ----------------

extern "C" void kernel_launch(void* const* d_in, const int* in_sizes, int n_in,
                              void* d_out, int out_size, void* d_ws, size_t ws_size,
                              hipStream_t stream) {
    const float* x = (const float*)d_in[0];
    const int* ei = (const int*)d_in[1];
    const float* W1 = (const float*)d_in[2];
    const float* a1s = (const float*)d_in[3];
    const float* a1d = (const float*)d_in[4];
    const float* b1 = (const float*)d_in[5];
    const float* W2 = (const float*)d_in[6];
    const float* a2s = (const float*)d_in[7];
    const float* a2d = (const float*)d_in[8];
    const float* b2 = (const float*)d_in[9];
    const float* Wl = (const float*)d_in[10];
    const float* bl = (const float*)d_in[11];
    float* out = (float*)d_out;

    char* w = (char*)d_ws;
    ushortT* B0 = (ushortT*)w; w += (size_t)PAD_M * CD * 2;
    ushortT* B1 = (ushortT*)w; w += (size_t)PAD_M * CD * 2;
    ushortT* B2 = (ushortT*)w; w += (size_t)PAD_M * CD * 2;
    ushortT* W1t = (ushortT*)w; w += (size_t)CD * CD * 2;
    ushortT* W2t = (ushortT*)w; w += (size_t)CD * CD * 2;
    ushortT* Wlt = (ushortT*)w; w += (size_t)CD * CD * 2;
    float* asA = (float*)w; w += (size_t)NN * 4;
    float* adA = (float*)w; w += (size_t)NN * 4;
    float* asB = (float*)w; w += (size_t)NN * 4;
    float* adB = (float*)w; w += (size_t)NN * 4;
    int* deg = (int*)w; w += (size_t)NN * 4;
    int* fill_pos = (int*)w; w += (size_t)NN * 4;
    int* srcs = (int*)w; w += (size_t)ET * 4;
    int* bsum = (int*)w; w += 1024;
    int* row_start = (int*)w; w += (size_t)(NN + 1) * 4;

    // fused preprocessing: casts + deg/alpha init
    prep_kernel<<<PREP_END, 256, 0, stream>>>(x, W1, W2, Wl, B0, W1t, W2t, Wlt,
                                              deg, asA, adA, asB, adB);

    // CSR build
    count_deg_kernel<<<(EE + 255) / 256, 256, 0, stream>>>(ei, deg);
    scan_part<<<NB, 256, 0, stream>>>(deg, bsum);
    scan_fill<<<NB, 256, 0, stream>>>(deg, bsum, row_start, fill_pos);
    fill_csr_kernel<<<(ET + 255) / 256, 256, 0, stream>>>(ei, fill_pos, srcs);

    int ggrid = (PAD_M / 128) * 4;   // 1568 blocks of 128 rows x 64 cols
    int nwave_blocks = (NN + 3) / 4;

    // Layer 1 (alpha fused into GEMM epilogue, A buffers)
    gemm_mfma<0, 1><<<ggrid, 256, 0, stream>>>(B0, W1t, nullptr, nullptr, B1,
                                               a1s, a1d, asA, adA, NN);
    gat_agg<<<nwave_blocks, 256, 0, stream>>>(B1, asA, adA, row_start, srcs, b1, B2);

    // Layer 2 (B buffers — pre-zeroed in prep, no zero dispatch needed)
    gemm_mfma<0, 1><<<ggrid, 256, 0, stream>>>(B2, W2t, nullptr, nullptr, B1,
                                               a2s, a2d, asB, adB, NN);
    gat_agg<<<nwave_blocks, 256, 0, stream>>>(B1, asB, adB, row_start, srcs, b2, B0);

    // Final linear: out = B0 @ Wlt^T + bl (fp32 out)
    gemm_mfma<1, 0><<<ggrid, 256, 0, stream>>>(B0, Wlt, bl, out, nullptr,
                                               nullptr, nullptr, nullptr, nullptr, NN);
}

// Round 8
// 294.573 us; speedup vs baseline: 1.1046x; 1.0019x over previous
//
#include <hip/hip_runtime.h>

#define NN 50000
#define EE 300000
#define ET (EE + NN)   // edges + self loops = 350000
#define CD 256
#define PAD_M 50176    // 392 * 128, covers gemm tile over-read
#define NB 196         // scan blocks: 196*256 = 50176 >= NN

typedef unsigned short ushortT;
typedef short bf16x8 __attribute__((ext_vector_type(8)));
typedef float f32x4 __attribute__((ext_vector_type(4)));

__device__ __forceinline__ ushortT f2b(float f) {
    unsigned u = __builtin_bit_cast(unsigned, f);
    unsigned r = (u + 0x7FFFu + ((u >> 16) & 1u)) >> 16;
    return (ushortT)r;
}
__device__ __forceinline__ float b2f(ushortT b) {
    return __builtin_bit_cast(float, ((unsigned)b) << 16);
}

// ---------------- alpha-vector precompute: wXs = W @ a_src (row dots) ------
// (x@W)·a == x·(W@a): lets alpha1 be computed in prep (x in registers) and
// alpha2 in agg1's epilogue (fp32 acc in registers) — GEMM epilogues lose
// their shuffle-reduce + atomicAdd alpha paths entirely.
// grid 128: blocks [0,64) -> W1 rows, [64,128) -> W2 rows; wave per row.

__global__ __launch_bounds__(256) void wvec_kernel(
    const float* __restrict__ W1, const float* __restrict__ a1s,
    const float* __restrict__ a1d, const float* __restrict__ W2,
    const float* __restrict__ a2s, const float* __restrict__ a2d,
    float* __restrict__ w1s, float* __restrict__ w1d,
    float* __restrict__ w2s, float* __restrict__ w2d) {
    int b = blockIdx.x;
    const float* W = (b < 64) ? W1 : W2;
    const float* vs = (b < 64) ? a1s : a2s;
    const float* vd = (b < 64) ? a1d : a2d;
    float* os = (b < 64) ? w1s : w2s;
    float* od = (b < 64) ? w1d : w2d;
    int r = (b & 63) * 4 + (threadIdx.x >> 6);
    int lane = threadIdx.x & 63;
    float4 wv = *(const float4*)(W + (size_t)r * CD + lane * 4);
    float4 s4 = *(const float4*)(vs + lane * 4);
    float4 d4 = *(const float4*)(vd + lane * 4);
    float ss = wv.x * s4.x + wv.y * s4.y + wv.z * s4.z + wv.w * s4.w;
    float dd = wv.x * d4.x + wv.y * d4.y + wv.z * d4.z + wv.w * d4.w;
#pragma unroll
    for (int off = 1; off < 64; off <<= 1) {
        ss += __shfl_xor(ss, off);
        dd += __shfl_xor(dd, off);
    }
    if (lane == 0) {
        os[r] = ss;
        od[r] = dd;
    }
}

// ---------------- fused preprocessing ----------------
// [0,12500)      x rows: cast->bf16 AND alpha1 = x·w1s / x·w1d (wave per row)
// [12500,12564)  transpose-cast W1 -> W1t
// [12564,12628)  transpose-cast W2 -> W2t
// [12628,12692)  straight-cast Wl -> Wlt
// [12692,12888)  init deg=1
#define PREP_X 12500
#define PREP_W1 12564
#define PREP_W2 12628
#define PREP_WL 12692
#define PREP_END 12888

__global__ __launch_bounds__(256) void prep_kernel(
    const float* __restrict__ x, const float* __restrict__ W1,
    const float* __restrict__ W2, const float* __restrict__ Wl,
    ushortT* __restrict__ B0, ushortT* __restrict__ W1t,
    ushortT* __restrict__ W2t, ushortT* __restrict__ Wlt,
    int* __restrict__ deg, const float* __restrict__ w1s,
    const float* __restrict__ w1d, float* __restrict__ as1,
    float* __restrict__ ad1) {
    __shared__ float t[32][33];
    int b = blockIdx.x, tidx = threadIdx.x;
    if (b < PREP_X) {
        int node = b * 4 + (tidx >> 6);
        int lane = tidx & 63;
        float4 v = *(const float4*)(x + (size_t)node * CD + lane * 4);
        ushort4 o;
        o.x = f2b(v.x); o.y = f2b(v.y); o.z = f2b(v.z); o.w = f2b(v.w);
        *(ushort4*)(B0 + (size_t)node * CD + lane * 4) = o;
        float4 s4 = *(const float4*)(w1s + lane * 4);
        float4 d4 = *(const float4*)(w1d + lane * 4);
        float ss = v.x * s4.x + v.y * s4.y + v.z * s4.z + v.w * s4.w;
        float dd = v.x * d4.x + v.y * d4.y + v.z * d4.z + v.w * d4.w;
#pragma unroll
        for (int off = 1; off < 64; off <<= 1) {
            ss += __shfl_xor(ss, off);
            dd += __shfl_xor(dd, off);
        }
        if (lane == 0) {
            as1[node] = ss;
            ad1[node] = dd;
        }
    } else if (b < PREP_W2) {
        const float* W = (b < PREP_W1) ? W1 : W2;
        ushortT* Bt = (b < PREP_W1) ? W1t : W2t;
        int rel = b - ((b < PREP_W1) ? PREP_X : PREP_W1);
        int bx = (rel & 7) * 32;   // k base
        int by = (rel >> 3) * 32;  // n base
        int xx = tidx & 31, yy = tidx >> 5;
        for (int y = yy; y < 32; y += 8) t[y][xx] = W[(size_t)(bx + y) * CD + by + xx];
        __syncthreads();
        for (int y = yy; y < 32; y += 8)
            Bt[(size_t)(by + y) * CD + bx + xx] = f2b(t[xx][y]);
    } else if (b < PREP_WL) {
        int id = (b - PREP_W2) * 256 + tidx;
        float4 v = *(const float4*)(Wl + (size_t)id * 4);
        ushort4 o;
        o.x = f2b(v.x); o.y = f2b(v.y); o.z = f2b(v.z); o.w = f2b(v.w);
        *(ushort4*)(Wlt + (size_t)id * 4) = o;
    } else {
        int i = (b - PREP_WL) * 256 + tidx;
        if (i < NN) deg[i] = 1;  // self loop
    }
}

// ---------------- CSR build ----------------

__global__ void count_deg_kernel(const int* __restrict__ ei, int* __restrict__ deg) {
    int i = blockIdx.x * blockDim.x + threadIdx.x;
    if (i < EE) atomicAdd(&deg[ei[EE + i]], 1);  // dst row of edge_index
}

__global__ __launch_bounds__(256) void scan_part(const int* __restrict__ deg,
                                                 int* __restrict__ bsum) {
    int i = blockIdx.x * 256 + threadIdx.x;
    int v = (i < NN) ? deg[i] : 0;
#pragma unroll
    for (int off = 32; off > 0; off >>= 1) v += __shfl_down(v, off);
    __shared__ int w[4];
    if ((threadIdx.x & 63) == 0) w[threadIdx.x >> 6] = v;
    __syncthreads();
    if (threadIdx.x == 0) bsum[blockIdx.x] = w[0] + w[1] + w[2] + w[3];
}

// scan_fill with the top-level 196-partial scan folded in.
__global__ __launch_bounds__(256) void scan_fill(const int* __restrict__ deg,
                                                 const int* __restrict__ bsum,
                                                 int* __restrict__ row_start,
                                                 int* __restrict__ fill_pos) {
    __shared__ int s[256];
    int t = threadIdx.x;
    int bv = (t < NB) ? bsum[t] : 0;
    s[t] = bv;
    __syncthreads();
    for (int off = 1; off < 256; off <<= 1) {
        int x = s[t];
        int y = (t >= off) ? s[t - off] : 0;
        __syncthreads();
        s[t] = x + y;
        __syncthreads();
    }
    int boff = s[blockIdx.x] - bsum[blockIdx.x];  // exclusive prefix for this block
    __syncthreads();
    int i = blockIdx.x * 256 + t;
    int v = (i < NN) ? deg[i] : 0;
    s[t] = v;
    __syncthreads();
    for (int off = 1; off < 256; off <<= 1) {
        int x = s[t];
        int y = (t >= off) ? s[t - off] : 0;
        __syncthreads();
        s[t] = x + y;
        __syncthreads();
    }
    int excl = s[t] - v + boff;
    if (i < NN) {
        row_start[i] = excl;
        fill_pos[i] = excl;
    }
    if (blockIdx.x == 0 && t == 0) row_start[NN] = ET;
}

__global__ void fill_csr_kernel(const int* __restrict__ ei, int* __restrict__ fill_pos,
                                int* __restrict__ srcs) {
    int i = blockIdx.x * blockDim.x + threadIdx.x;
    if (i < EE) {
        int s = ei[i];
        int d = ei[EE + i];
        int p = atomicAdd(&fill_pos[d], 1);
        srcs[p] = s;
    } else if (i < ET) {
        int n = i - EE;
        int p = atomicAdd(&fill_pos[n], 1);
        srcs[p] = n;  // self loop
    }
}

// ---------------- bf16 MFMA GEMM: C[M,256] = A[M,256] @ Bt^T ----------------
// Block = 128 rows x 64 cols, 1-D grid 1568, swizzled so the 4 col-blocks
// sharing the same A rows are temporally adjacent (L2/L3 A-reuse).
// All A fragments hoisted into registers concurrently with B global_load_lds
// staging; K-loop is pure LDS+MFMA. B LDS layout: column-permuted (slot n ->
// col (n&15)*4+(n>>4)) so lane l15 owns 4 contiguous output cols -> packed
// 8B/16B stores (this killed R5's 2x write amplification); 16B-chunk xor
// swizzle for bank conflicts (measured 0). No alpha epilogue (moved out).

template <int OUTF32>
__global__ __launch_bounds__(256, 4) void gemm_mfma(const ushortT* __restrict__ A,
                                                    const ushortT* __restrict__ Bt,
                                                    const float* __restrict__ bias,
                                                    float* __restrict__ outF,
                                                    ushortT* __restrict__ outB,
                                                    int M) {
    __shared__ ushortT Bs[64 * 256];  // 32 KB
    int tid = threadIdx.x;
    int wave = tid >> 6, lane = tid & 63;
    int wm = wave * 32;                    // wave's 32-row slice of 128-row block
    int id = blockIdx.x;
    int bm = (id >> 2) * 128, bn = (id & 3) * 64;
    int l15 = lane & 15, quad = lane >> 4;

    // ---- B staging: 64 slots x 32 chunks = 2048 16B chunks, 8 rounds ----
#pragma unroll
    for (int p = 0; p < 8; ++p) {
        int c = p * 256 + tid;             // lane-linear flat chunk id
        int slot = c >> 5;                 // LDS slot (permuted col)
        int piece = c & 31;
        int col = (slot & 15) * 4 + (slot >> 4);   // actual col for this slot
        int spiece = piece ^ (slot & 31);  // physical chunk p holds data chunk p^slot
        const ushortT* gb = Bt + (size_t)(bn + col) * CD + spiece * 8;
        __builtin_amdgcn_global_load_lds(
            (const __attribute__((address_space(1))) void*)gb,
            (__attribute__((address_space(3))) void*)(Bs + (size_t)(p * 256 + wave * 64) * 8),
            16, 0, 0);
    }

    // ---- hoist ALL A fragments (16 independent 16B loads in flight) ----
    bf16x8 a[2][8];
#pragma unroll
    for (int kk = 0; kk < 8; ++kk)
#pragma unroll
        for (int i = 0; i < 2; ++i)
            a[i][kk] = *(const bf16x8*)(A + (size_t)(bm + wm + i * 16 + l15) * CD + kk * 32 + quad * 8);

    __syncthreads();

    f32x4 acc[2][4] = {};

    // ---- K loop: pure LDS + MFMA ----
#pragma unroll
    for (int kk = 0; kk < 8; ++kk) {
        bf16x8 b[4];
        int kc = kk * 4 + quad;  // data chunk index within slot
#pragma unroll
        for (int j = 0; j < 4; ++j) {
            int slot = j * 16 + l15;
            b[j] = *(const bf16x8*)(Bs + (size_t)slot * 256 + (size_t)(kc ^ (slot & 31)) * 8);
        }
#pragma unroll
        for (int i = 0; i < 2; ++i)
#pragma unroll
            for (int j = 0; j < 4; ++j)
                acc[i][j] = __builtin_amdgcn_mfma_f32_16x16x32_bf16(a[i][kk], b[j], acc[i][j], 0, 0, 0);
    }

    // ---- epilogue: lane l15 owns 4 contiguous cols bn+4*l15.. across j ----
    int colb = bn + l15 * 4;
#pragma unroll
    for (int i = 0; i < 2; ++i) {
#pragma unroll
        for (int r = 0; r < 4; ++r) {
            int row = bm + wm + i * 16 + quad * 4 + r;
            if (OUTF32) {
                if (row < M) {
                    float4 bv = *(const float4*)(bias + colb);
                    float4 v;
                    v.x = acc[i][0][r] + bv.x;
                    v.y = acc[i][1][r] + bv.y;
                    v.z = acc[i][2][r] + bv.z;
                    v.w = acc[i][3][r] + bv.w;
                    *(float4*)(outF + (size_t)row * CD + colb) = v;
                }
            } else {
                ushort4 o;
                o.x = f2b(acc[i][0][r]);
                o.y = f2b(acc[i][1][r]);
                o.z = f2b(acc[i][2][r]);
                o.w = f2b(acc[i][3][r]);
                *(ushort4*)(outB + (size_t)row * CD + colb) = o;  // ws padded
            }
        }
    }
}

// ---------------- GAT aggregation: one wave per dst node (bf16 h, bf16 out) --
// ALPHA2=1: also emit next layer's alpha from the fp32 pre-cast row:
//   as2[n] = relu_row · w2s, ad2[n] = relu_row · w2d  ((h@W2)·a == h·(W2@a))

__device__ __forceinline__ float lrelu02(float x) { return x > 0.f ? x : 0.2f * x; }

template <int ALPHA2>
__global__ __launch_bounds__(256) void gat_agg(const ushortT* __restrict__ h,
                                               const float* __restrict__ as_,
                                               const float* __restrict__ ad_,
                                               const int* __restrict__ row_start,
                                               const int* __restrict__ srcs,
                                               const float* __restrict__ bias,
                                               ushortT* __restrict__ out,
                                               const float* __restrict__ w2s,
                                               const float* __restrict__ w2d,
                                               float* __restrict__ as_n,
                                               float* __restrict__ ad_n) {
    int node = blockIdx.x * 4 + (threadIdx.x >> 6);
    int lane = threadIdx.x & 63;
    if (node >= NN) return;
    int rs = row_start[node];
    int re = row_start[node + 1];
    int deg = re - rs;
    float adst = ad_[node];

    float a0 = 0.f, a1 = 0.f, a2 = 0.f, a3 = 0.f;

    if (deg <= 64) {
        // ---- fast path: softmax entirely in-register, ILP-8 gather ----
        int s_lane = srcs[rs + ((lane < deg) ? lane : 0)];
        float e = (lane < deg) ? lrelu02(as_[s_lane] + adst) : -1e30f;
        float m = e;
#pragma unroll
        for (int off = 1; off < 64; off <<= 1) m = fmaxf(m, __shfl_xor(m, off));
        float ex = (lane < deg) ? __expf(e - m) : 0.f;
        float den = ex;
#pragma unroll
        for (int off = 1; off < 64; off <<= 1) den += __shfl_xor(den, off);
        float wl = ex / den;  // per-lane edge weight (0 for invalid lanes)

        for (int kk = 0; kk < deg; kk += 8) {
            int s[8];
            float w[8];
#pragma unroll
            for (int t = 0; t < 8; ++t) {
                int idx = kk + t;                 // wave-uniform
                int ii = (idx < deg) ? idx : kk;  // clamp to a valid lane
                int sv = __shfl(s_lane, ii);
                float wv = __shfl(wl, ii);
                s[t] = sv;
                w[t] = (idx < deg) ? wv : 0.f;
            }
            ushort4 hv[8];
#pragma unroll
            for (int t = 0; t < 8; ++t)
                hv[t] = *(const ushort4*)(h + (size_t)s[t] * CD + lane * 4);
#pragma unroll
            for (int t = 0; t < 8; ++t) {
                a0 += w[t] * b2f(hv[t].x);
                a1 += w[t] * b2f(hv[t].y);
                a2 += w[t] * b2f(hv[t].z);
                a3 += w[t] * b2f(hv[t].w);
            }
        }
    } else {
        // ---- generic path (deg > 64): strided loops ----
        float m = -1e30f;
        for (int k = rs + lane; k < re; k += 64) {
            float e = lrelu02(as_[srcs[k]] + adst);
            m = fmaxf(m, e);
        }
#pragma unroll
        for (int off = 1; off < 64; off <<= 1) m = fmaxf(m, __shfl_xor(m, off));
        float den = 0.f;
        for (int k = rs + lane; k < re; k += 64) {
            float e = lrelu02(as_[srcs[k]] + adst);
            den += __expf(e - m);
        }
#pragma unroll
        for (int off = 1; off < 64; off <<= 1) den += __shfl_xor(den, off);
        float inv_den = 1.f / den;
        for (int k = rs; k < re; ++k) {
            int s = srcs[k];
            float e = lrelu02(as_[s] + adst);
            float w = __expf(e - m) * inv_den;
            ushort4 hv = *(const ushort4*)(h + (size_t)s * CD + lane * 4);
            a0 += w * b2f(hv.x);
            a1 += w * b2f(hv.y);
            a2 += w * b2f(hv.z);
            a3 += w * b2f(hv.w);
        }
    }

    float4 b4 = *(const float4*)(bias + lane * 4);
    a0 = fmaxf(a0 + b4.x, 0.f);  // bias + relu (both convs feed relu)
    a1 = fmaxf(a1 + b4.y, 0.f);
    a2 = fmaxf(a2 + b4.z, 0.f);
    a3 = fmaxf(a3 + b4.w, 0.f);
    ushort4 o;
    o.x = f2b(a0);
    o.y = f2b(a1);
    o.z = f2b(a2);
    o.w = f2b(a3);
    *(ushort4*)(out + (size_t)node * CD + lane * 4) = o;

    if (ALPHA2) {
        float4 s4 = *(const float4*)(w2s + lane * 4);
        float4 d4 = *(const float4*)(w2d + lane * 4);
        float ss = a0 * s4.x + a1 * s4.y + a2 * s4.z + a3 * s4.w;
        float dd = a0 * d4.x + a1 * d4.y + a2 * d4.z + a3 * d4.w;
#pragma unroll
        for (int off = 1; off < 64; off <<= 1) {
            ss += __shfl_xor(ss, off);
            dd += __shfl_xor(dd, off);
        }
        if (lane == 0) {
            as_n[node] = ss;
            ad_n[node] = dd;
        }
    }
}

// ---------------- launch ----------------

extern "C" void kernel_launch(void* const* d_in, const int* in_sizes, int n_in,
                              void* d_out, int out_size, void* d_ws, size_t ws_size,
                              hipStream_t stream) {
    const float* x = (const float*)d_in[0];
    const int* ei = (const int*)d_in[1];
    const float* W1 = (const float*)d_in[2];
    const float* a1s = (const float*)d_in[3];
    const float* a1d = (const float*)d_in[4];
    const float* b1 = (const float*)d_in[5];
    const float* W2 = (const float*)d_in[6];
    const float* a2s = (const float*)d_in[7];
    const float* a2d = (const float*)d_in[8];
    const float* b2 = (const float*)d_in[9];
    const float* Wl = (const float*)d_in[10];
    const float* bl = (const float*)d_in[11];
    float* out = (float*)d_out;

    char* w = (char*)d_ws;
    ushortT* B0 = (ushortT*)w; w += (size_t)PAD_M * CD * 2;
    ushortT* B1 = (ushortT*)w; w += (size_t)PAD_M * CD * 2;
    ushortT* B2 = (ushortT*)w; w += (size_t)PAD_M * CD * 2;
    ushortT* W1t = (ushortT*)w; w += (size_t)CD * CD * 2;
    ushortT* W2t = (ushortT*)w; w += (size_t)CD * CD * 2;
    ushortT* Wlt = (ushortT*)w; w += (size_t)CD * CD * 2;
    float* as1 = (float*)w; w += (size_t)NN * 4;
    float* ad1 = (float*)w; w += (size_t)NN * 4;
    float* as2 = (float*)w; w += (size_t)NN * 4;
    float* ad2 = (float*)w; w += (size_t)NN * 4;
    float* w1s = (float*)w; w += CD * 4;
    float* w1d = (float*)w; w += CD * 4;
    float* w2s = (float*)w; w += CD * 4;
    float* w2d = (float*)w; w += CD * 4;
    int* deg = (int*)w; w += (size_t)NN * 4;
    int* fill_pos = (int*)w; w += (size_t)NN * 4;
    int* srcs = (int*)w; w += (size_t)ET * 4;
    int* bsum = (int*)w; w += 1024;
    int* row_start = (int*)w; w += (size_t)(NN + 1) * 4;

    // alpha-vector precompute (must precede prep, which uses w1s/w1d)
    wvec_kernel<<<128, 256, 0, stream>>>(W1, a1s, a1d, W2, a2s, a2d,
                                         w1s, w1d, w2s, w2d);

    // fused preprocessing: x cast + alpha1, W transposes, Wl cast, deg init
    prep_kernel<<<PREP_END, 256, 0, stream>>>(x, W1, W2, Wl, B0, W1t, W2t, Wlt,
                                              deg, w1s, w1d, as1, ad1);

    // CSR build
    count_deg_kernel<<<(EE + 255) / 256, 256, 0, stream>>>(ei, deg);
    scan_part<<<NB, 256, 0, stream>>>(deg, bsum);
    scan_fill<<<NB, 256, 0, stream>>>(deg, bsum, row_start, fill_pos);
    fill_csr_kernel<<<(ET + 255) / 256, 256, 0, stream>>>(ei, fill_pos, srcs);

    int ggrid = (PAD_M / 128) * 4;   // 1568 blocks of 128 rows x 64 cols
    int nwave_blocks = (NN + 3) / 4;

    // Layer 1
    gemm_mfma<0><<<ggrid, 256, 0, stream>>>(B0, W1t, nullptr, nullptr, B1, NN);
    gat_agg<1><<<nwave_blocks, 256, 0, stream>>>(B1, as1, ad1, row_start, srcs,
                                                 b1, B2, w2s, w2d, as2, ad2);

    // Layer 2
    gemm_mfma<0><<<ggrid, 256, 0, stream>>>(B2, W2t, nullptr, nullptr, B1, NN);
    gat_agg<0><<<nwave_blocks, 256, 0, stream>>>(B1, as2, ad2, row_start, srcs,
                                                 b2, B0, nullptr, nullptr,
                                                 nullptr, nullptr);

    // Final linear: out = B0 @ Wlt^T + bl (fp32 out)
    gemm_mfma<1><<<ggrid, 256, 0, stream>>>(B0, Wlt, bl, out, nullptr, NN);
}